// Round 7
// baseline (95764.142 us; speedup 1.0000x reference)
//
#include <hip/hip_runtime.h>
#include <hip/hip_fp16.h>
#include <stdint.h>

// ---------------------------------------------------------------------------
// SequentialEMGPoseLSTM: 2-layer LSTM (H=256, B=64, T=4096) + LeakyReLU+Linear
//
// R9: R3 base (best measured: 577us steady) + two isolated deltas.
// Post-mortem R8: co-inlining both MATH variants in ONE kernel made the
// allocator cover both paths at once -> weight regs spilled to SCRATCH ->
// 8.7GB/dispatch of spill reloads (FETCH 71MB->8.7GB, dur 10ms). Guide rule
// #19 violation; the A/B measured nothing.
//  - A/B redone correctly: fused_kernel is a template<MATH> __global__;
//    <0> (v_dot2) and <1> (v_fma_mix via fmaf((float)h,(float)h,acc)) are
//    SEPARATE kernels with SEPARATE register allocations, launched by
//    dispatch parity. Per-dispatch rocprof durations are the readout for
//    the "v_dot2 issues at quarter rate" hypothesis (R3/R6/R7 cycle
//    accounting fits ~8 cyc/dot2; fma_mix would be 2x2cyc for same work).
//  - Step barrier = lgkm-only (R7-verified numerics-safe): removes the
//    per-step s_waitcnt vmcnt(0) drain of h1w stores / xw loads. End-of-
//    kernel drain guarantees cross-dispatch visibility.
//  - Everything else is R3 verbatim (incl. the 4096-block one-tile MFMA
//    GEMM grid, which measured best).
// ---------------------------------------------------------------------------

#define T_SEQ 4096
#define NB    64
#define HID   256
#define G4    1024
#define INCH  16
#define OC    20

typedef _Float16 h2v   __attribute__((ext_vector_type(2)));
typedef _Float16 f16x8 __attribute__((ext_vector_type(8)));
typedef float    f32x4 __attribute__((ext_vector_type(4)));

__device__ __forceinline__ float fdot2(uint32_t a, uint32_t b, float c) {
  return __builtin_amdgcn_fdot2(__builtin_bit_cast(h2v, a),
                                __builtin_bit_cast(h2v, b), c, false);
}
// MATH=0: v_dot2_f32_f16. MATH=1: 2x v_fma_mix_f32 (f32 accumulate; same
// numerics as dot2's internal f32 accumulate).
template <int MATH>
__device__ __forceinline__ float dot2t(uint32_t a, uint32_t b, float c) {
  if constexpr (MATH == 0) {
    return fdot2(a, b, c);
  } else {
    h2v av = __builtin_bit_cast(h2v, a);
    h2v bv = __builtin_bit_cast(h2v, b);
    c = fmaf((float)av.x, (float)bv.x, c);
    c = fmaf((float)av.y, (float)bv.y, c);
    return c;
  }
}
__device__ __forceinline__ float sigf(float x) {
  x = fminf(fmaxf(x, -30.f), 30.f);
  return 1.f / (1.f + __expf(-x));
}
__device__ __forceinline__ float tanhf_fast(float x) {
  x = fminf(fmaxf(x, -15.f), 15.f);
  float e = __expf(-2.f * x);
  return (1.f - e) / (1.f + e);
}
// Sum across the 4 slices of a quad (lane bits 0-1) on the VALU pipe.
__device__ __forceinline__ float quad_sum(float a) {
  a += __int_as_float(
      __builtin_amdgcn_update_dpp(0, __float_as_int(a), 0xB1, 0xF, 0xF, true));
  a += __int_as_float(
      __builtin_amdgcn_update_dpp(0, __float_as_int(a), 0x4E, 0xF, 0xF, true));
  return a;
}

#define PIN(x) asm volatile("" : "+v"(x))
// LDS-only step barrier: no vmcnt drain. Global ops (h1w stores, xw loads,
// y stores) float across steps; the compiler still inserts precise vmcnt
// waits before any USE of a loaded value, and kernel end drains all stores
// before the next dispatch reads them. R7-verified numerics-safe.
#define STEP_BARRIER() asm volatile("s_waitcnt lgkmcnt(0)\n\ts_barrier" ::: "memory")

// Padded LDS layouts (all offsets 16B-aligned):
//  w   : 256 rows x 264 halves (rows 768..1023 of Whh). Row r at bank 4r%32.
//  hbuf: 2 x (4 slices x 72 halves). Slice s at bank offset 4s.
//  abuf: 2 x (8 chunks x 40 halves). Chunk ks at bank 20ks%32.
struct SmemR {
  __half w[256 * 264];        // 135168 B
  uint32_t hbuf[2][144];      // 1152 B
  union {
    uint32_t xb[512 * 8];     // layer0: packed x pairs [tt][dp], Tc<=512
    struct {
      __half abuf[2][320];    // layer1: leaky(h2), padded chunks
      __half whd[20 * 264];   // head weights, padded rows
      float  bh[20];
    } h1;
  } u;
};
struct SmemG {
  __half a[128 * 40];
  __half b[64 * 40];
};
union Smem { SmemR r; SmemG g; };

struct Params {
  const float* x;
  const __half *wh0, *wh1, *wi0, *wi1, *whd;
  const float  *bs0, *bs1, *bhd;
  float *h0s, *c0s, *h1s, *c1s;
  __half* h1w; const __half* h1r;
  float* xww;  const float* xwr;
  float* y;
  int L, Tc, nch;
};

// ---------------------------------------------------------------------------
// Recurrent role: one block == one batch chain. 512 threads (2 waves/SIMD).
// slice = tid&3 covers k in [64*slice, 64*slice+64); rg = tid>>2 (0..127).
// Thread handles gate rows r = rg + 128*j, j=0..7 (j<6 reg, j>=6 LDS).
// Owners: slice0 -> channel rg, slice1 -> channel rg+128.
// ---------------------------------------------------------------------------
template <int LAYER, int MATH>
__device__ void role_rec(SmemR& S, int ch, const Params& P, int b) {
  if (ch < 0 || ch >= P.nch) return;
  const int tid   = threadIdx.x;
  const int slice = tid & 3;
  const int rg    = tid >> 2;
  const int Tc    = P.Tc;
  const __half* whh = (LAYER == 0) ? P.wh0 : P.wh1;

  // Stage LDS-resident weight rows 768..1023 into padded layout.
  for (int i = tid; i < 8192; i += 512) {
    int R = i >> 5, oct = i & 31;
    *(uint4*)&S.w[R * 264 + oct * 8] =
        *((const uint4*)(whh + (768 + R) * 256) + oct);
  }
  const int t0 = ch * Tc;
  if (LAYER == 0) {
    for (int i = tid; i < Tc * 8; i += 512) {
      int dp = i / Tc, tt = i - dp * Tc;
      float v0 = P.x[(b * INCH + 2 * dp) * T_SEQ + t0 + tt];
      float v1 = P.x[(b * INCH + 2 * dp + 1) * T_SEQ + t0 + tt];
      uint32_t pv = (uint32_t)__half_as_ushort(__float2half(v0)) |
                    ((uint32_t)__half_as_ushort(__float2half(v1)) << 16);
      S.u.xb[tt * 8 + dp] = pv;
    }
  } else {
    for (int i = tid; i < OC * 256; i += 512) {
      int o = i >> 8, k = i & 255;
      S.u.h1.whd[o * 264 + k] = P.whd[i];
    }
    if (tid < OC) S.u.h1.bh[tid] = P.bhd[tid];
  }

  // Register-resident weights: rows j=0..5, 64 halves each (32 packed u32).
  uint32_t wr[6][32];
#pragma unroll
  for (int j = 0; j < 6; j++) {
    const uint4* p = (const uint4*)(whh + (rg + 128 * j) * 256 + slice * 64);
#pragma unroll
    for (int q = 0; q < 8; q++) {
      uint4 v = p[q];
      wr[j][4 * q] = v.x; wr[j][4 * q + 1] = v.y;
      wr[j][4 * q + 2] = v.z; wr[j][4 * q + 3] = v.w;
    }
  }
#pragma unroll
  for (int j = 0; j < 6; j++)
#pragma unroll
    for (int q = 0; q < 32; q++) PIN(wr[j][q]);

  uint32_t wx[8][2];
  if (LAYER == 0) {
#pragma unroll
    for (int j = 0; j < 8; j++) {
      const uint32_t* p = (const uint32_t*)(P.wi0 + (rg + 128 * j) * INCH + slice * 4);
      wx[j][0] = p[0]; wx[j][1] = p[1];
    }
#pragma unroll
    for (int j = 0; j < 8; j++) { PIN(wx[j][0]); PIN(wx[j][1]); }
  }

  // Owner state: slice0 -> channel rg; slice1 -> channel rg+128 (fp32 h,c).
  const bool own = (slice < 2);
  const int chn = rg + ((slice & 1) << 7);
  float* hs = (LAYER == 0) ? P.h0s : P.h1s;
  float* cs = (LAYER == 0) ? P.c0s : P.c1s;
  float bs4[4] = {0.f, 0.f, 0.f, 0.f};
  float hO = 0.f, cO = 0.f;
  if (own) {
    const float* bsg = (LAYER == 0) ? P.bs0 : P.bs1;
#pragma unroll
    for (int k = 0; k < 4; k++) bs4[k] = bsg[chn + 256 * k];
    if (ch != 0) { hO = hs[b * 256 + chn]; cO = cs[b * 256 + chn]; }
    ((__half*)S.hbuf[0])[(chn >> 6) * 72 + (chn & 63)] = __float2half(hO);
  }
  const float* xp = (LAYER == 1 && own) ? (P.xwr + (size_t)b * G4 + chn)
                                        : (const float*)nullptr;
  __syncthreads();

  const __half* hbA = (const __half*)S.hbuf[0] + slice * 72;
  const __half* hbB = (const __half*)S.hbuf[1] + slice * 72;
  __half hprev = __float2half(0.f);
  float xwv[4] = {0.f, 0.f, 0.f, 0.f};

  for (int tt = 0; tt < Tc; ++tt) {
    // Post-barrier zone: global ops retire under this step's compute (the
    // lgkm-only step barrier never drains them).
    if (LAYER == 0 && own && tt > 0)
      P.h1w[(size_t)((tt - 1) * NB + b) * 256 + chn] = hprev;
    if (LAYER == 1 && own) {
      const float* q = xp + (size_t)tt * (NB * G4);
      xwv[0] = q[0]; xwv[1] = q[256]; xwv[2] = q[512]; xwv[3] = q[768];
    }

    const __half* hb = (tt & 1) ? hbB : hbA;
    float acc[8];
#pragma unroll
    for (int j = 0; j < 8; j++) acc[j] = 0.f;

#pragma unroll
    for (int hf = 0; hf < 2; ++hf) {
      uint32_t hh[16];
      const uint4* hp = (const uint4*)(hb + hf * 32);
#pragma unroll
      for (int q = 0; q < 4; q++) {
        uint4 v = hp[q];
        hh[4 * q] = v.x; hh[4 * q + 1] = v.y; hh[4 * q + 2] = v.z; hh[4 * q + 3] = v.w;
      }
#pragma unroll
      for (int j = 0; j < 6; j++) {
        float a = acc[j];
#pragma unroll
        for (int q = 0; q < 16; q++) a = dot2t<MATH>(wr[j][hf * 16 + q], hh[q], a);
        acc[j] = a;
      }
#pragma unroll
      for (int j = 6; j < 8; j++) {
        const uint4* wp =
            (const uint4*)&S.w[((j - 6) * 128 + rg) * 264 + slice * 64 + hf * 32];
        float a = acc[j];
#pragma unroll
        for (int q = 0; q < 4; q++) {
          uint4 v = wp[q];
          a = dot2t<MATH>(v.x, hh[4 * q], a);
          a = dot2t<MATH>(v.y, hh[4 * q + 1], a);
          a = dot2t<MATH>(v.z, hh[4 * q + 2], a);
          a = dot2t<MATH>(v.w, hh[4 * q + 3], a);
        }
        acc[j] = a;
      }
    }
    if (LAYER == 0) {
      uint32_t xv0 = S.u.xb[tt * 8 + 2 * slice];
      uint32_t xv1 = S.u.xb[tt * 8 + 2 * slice + 1];
#pragma unroll
      for (int j = 0; j < 8; j++) {
        acc[j] = dot2t<MATH>(wx[j][0], xv0, acc[j]);
        acc[j] = dot2t<MATH>(wx[j][1], xv1, acc[j]);
      }
    }
    // Reduce across the 4 slices on the VALU pipe (DPP).
#pragma unroll
    for (int j = 0; j < 8; j++) acc[j] = quad_sum(acc[j]);

    if (own) {
      const int o = slice & 1;  // 0 -> channel rg (even j), 1 -> rg+128 (odd j)
      float gi = acc[0 + o] + bs4[0];
      float gf = acc[2 + o] + bs4[1];
      float gg = acc[4 + o] + bs4[2];
      float go = acc[6 + o] + bs4[3];
      if (LAYER == 1) { gi += xwv[0]; gf += xwv[1]; gg += xwv[2]; go += xwv[3]; }
      float iv = sigf(gi), fv = sigf(gf);
      float gv = tanhf_fast(gg), ov = sigf(go);
      cO = fv * cO + iv * gv;
      hO = ov * tanhf_fast(cO);
      __half h16 = __float2half(hO);
      ((__half*)S.hbuf[(tt + 1) & 1])[(chn >> 6) * 72 + (chn & 63)] = h16;
      if (LAYER == 0) {
        hprev = h16;  // stored at top of next iteration (post-barrier)
      } else {
        float av = hO > 0.f ? hO : 0.01f * hO;
        S.u.h1.abuf[tt & 1][(chn >> 5) * 40 + (chn & 31)] = __float2half(av);
      }
    }
    STEP_BARRIER();  // lgkmcnt(0)+s_barrier only; no vmcnt drain

    // Head (layer1): 20 outputs x 8 lanes x 32 k. Reads abuf[tt&1] written
    // before the barrier; next overwrite of that buffer is 2 steps away and
    // gated by the intervening barrier. y-store floats into the next step.
    if (LAYER == 1 && tid < OC * 8) {
      int o = tid >> 3, ks = tid & 7;
      const uint4* wp = (const uint4*)&S.u.h1.whd[o * 264 + ks * 32];
      const uint4* ap = (const uint4*)&S.u.h1.abuf[tt & 1][ks * 40];
      float a = 0.f;
#pragma unroll
      for (int q = 0; q < 4; q++) {
        uint4 w4 = wp[q];
        uint4 a4 = ap[q];
        a = fdot2(w4.x, a4.x, a);
        a = fdot2(w4.y, a4.y, a);
        a = fdot2(w4.z, a4.z, a);
        a = fdot2(w4.w, a4.w, a);
      }
      a += __shfl_xor(a, 1);
      a += __shfl_xor(a, 2);
      a += __shfl_xor(a, 4);
      if (ks == 0) P.y[(b * OC + o) * T_SEQ + t0 + tt] = a + S.u.h1.bh[o];
    }
  }
  if (own) {
    if (LAYER == 0)
      P.h1w[(size_t)((Tc - 1) * NB + b) * 256 + chn] = hprev;
    hs[b * 256 + chn] = hO;
    cs[b * 256 + chn] = cO;
  }
}

// ---------------------------------------------------------------------------
// GEMM role: xw1[tb, g] = sum_k h1[tb,k] * Wih1[g,k], f16 MFMA, fp32 out.
// R3's proven grid: one 128x64 tile per block, Tc*8 blocks.
// ---------------------------------------------------------------------------
__device__ void role_gemm(SmemG& S, int chG, const Params& P) {
  if (chG < 0 || chG >= P.nch) return;
  const int bid = blockIdx.x - 128;
  const int nt = bid & 15, mt = bid >> 4;
  const int tb0 = mt * 128, g0 = nt * 64;
  const int tid = threadIdx.x, lane = tid & 63, w = tid >> 6;
  const int wm = w & 3, wn = w >> 2;

  f32x4 cacc[2][2] = {};
  for (int kk = 0; kk < 256; kk += 32) {
    __syncthreads();
    {
      int row = tid >> 2, q = tid & 3;
      const uint4* src = (const uint4*)(P.h1r + (tb0 + row) * 256 + kk + q * 8);
      *(uint4*)&S.a[row * 40 + q * 8] = *src;
    }
    if (tid < 256) {
      int row = tid >> 2, q = tid & 3;
      const uint4* src = (const uint4*)(P.wi1 + (g0 + row) * 256 + kk + q * 8);
      *(uint4*)&S.b[row * 40 + q * 8] = *src;
    }
    __syncthreads();
    f16x8 af[2], bf[2];
#pragma unroll
    for (int mi = 0; mi < 2; mi++)
      af[mi] = *(const f16x8*)&S.a[(wm * 32 + mi * 16 + (lane & 15)) * 40 + (lane >> 4) * 8];
#pragma unroll
    for (int ni = 0; ni < 2; ni++)
      bf[ni] = *(const f16x8*)&S.b[(wn * 32 + ni * 16 + (lane & 15)) * 40 + (lane >> 4) * 8];
#pragma unroll
    for (int mi = 0; mi < 2; mi++)
#pragma unroll
      for (int ni = 0; ni < 2; ni++)
        cacc[mi][ni] = __builtin_amdgcn_mfma_f32_16x16x32_f16(af[mi], bf[ni], cacc[mi][ni], 0, 0, 0);
  }
#pragma unroll
  for (int mi = 0; mi < 2; mi++)
#pragma unroll
    for (int ni = 0; ni < 2; ni++) {
      int m = wm * 32 + mi * 16 + (lane >> 4) * 4;
      int n = g0 + wn * 32 + ni * 16 + (lane & 15);
#pragma unroll
      for (int r = 0; r < 4; r++)
        P.xww[(size_t)(tb0 + m + r) * G4 + n] = cacc[mi][ni][r];
    }
}

// Separate __global__ instantiations per MATH: independent register
// allocations (rule #19 — R8's co-inlined A/B spilled to scratch).
template <int MATH>
__global__ __launch_bounds__(512)
__attribute__((amdgpu_waves_per_eu(2, 2)))
void fused_kernel(Params P) {
  __shared__ Smem S;
  int bid = blockIdx.x;
  if (bid < 64)        role_rec<0, MATH>(S.r, P.L, P, bid);
  else if (bid < 128)  role_rec<1, MATH>(S.r, P.L - 2, P, bid - 64);
  else                 role_gemm(S.g, P.L - 1, P);
}

// ---------------------------------------------------------------------------
__global__ void prep_kernel(const float* Wih0, const float* Whh0,
                            const float* bih0, const float* bhh0,
                            const float* Wih1, const float* Whh1,
                            const float* bih1, const float* bhh1,
                            const float* Whead, const float* bhead,
                            __half* wh0, __half* wh1, __half* wi1, __half* wi0,
                            __half* whd, float* bs0, float* bs1, float* bhd) {
  int i = blockIdx.x * blockDim.x + threadIdx.x;
  if (i < G4 * HID) {
    wh0[i] = __float2half(Whh0[i]);
    wh1[i] = __float2half(Whh1[i]);
    wi1[i] = __float2half(Wih1[i]);
  }
  if (i < G4 * INCH) wi0[i] = __float2half(Wih0[i]);
  if (i < OC * HID)  whd[i] = __float2half(Whead[i]);
  if (i < G4) { bs0[i] = bih0[i] + bhh0[i]; bs1[i] = bih1[i] + bhh1[i]; }
  if (i < OC) bhd[i] = bhead[i];
}

// ---------------------------------------------------------------------------
extern "C" void kernel_launch(void* const* d_in, const int* in_sizes, int n_in,
                              void* d_out, int out_size, void* d_ws, size_t ws_size,
                              hipStream_t stream) {
  const float* x     = (const float*)d_in[0];
  const float* Wih0  = (const float*)d_in[1];
  const float* Whh0  = (const float*)d_in[2];
  const float* bih0  = (const float*)d_in[3];
  const float* bhh0  = (const float*)d_in[4];
  const float* Wih1  = (const float*)d_in[5];
  const float* Whh1  = (const float*)d_in[6];
  const float* bih1  = (const float*)d_in[7];
  const float* bhh1  = (const float*)d_in[8];
  const float* Whead = (const float*)d_in[9];
  const float* bhead = (const float*)d_in[10];
  float* y = (float*)d_out;

  char* ws = (char*)d_ws;
  size_t cur = 0;
  auto alloc = [&](size_t sz) -> char* {
    char* p = ws + cur;
    cur = (cur + sz + 255) & ~(size_t)255;
    return p;
  };
  __half* wh0 = (__half*)alloc(G4 * HID * 2);
  __half* wh1 = (__half*)alloc(G4 * HID * 2);
  __half* wi1 = (__half*)alloc(G4 * HID * 2);
  __half* wi0 = (__half*)alloc(G4 * INCH * 2);
  __half* whd = (__half*)alloc(OC * HID * 2);
  float* bs0 = (float*)alloc(G4 * 4);
  float* bs1 = (float*)alloc(G4 * 4);
  float* bhd = (float*)alloc(OC * 4);
  float* h0s = (float*)alloc(NB * HID * 4);
  float* c0s = (float*)alloc(NB * HID * 4);
  float* h1s = (float*)alloc(NB * HID * 4);
  float* c1s = (float*)alloc(NB * HID * 4);
  size_t fixed = cur;

  int Tc = 512;
  while (Tc > 64) {
    size_t need = fixed + 2 * ((size_t)Tc * NB * HID * 2 + 512) +
                  2 * ((size_t)Tc * NB * G4 * 4 + 512);
    if (need <= ws_size) break;
    Tc >>= 1;
  }
  __half* h1buf[2];
  float* xwbuf[2];
  h1buf[0] = (__half*)alloc((size_t)Tc * NB * HID * 2);
  h1buf[1] = (__half*)alloc((size_t)Tc * NB * HID * 2);
  xwbuf[0] = (float*)alloc((size_t)Tc * NB * G4 * 4);
  xwbuf[1] = (float*)alloc((size_t)Tc * NB * G4 * 4);

  const int nch = T_SEQ / Tc;

  prep_kernel<<<(G4 * HID + 255) / 256, 256, 0, stream>>>(
      Wih0, Whh0, bih0, bhh0, Wih1, Whh1, bih1, bhh1, Whead, bhead,
      wh0, wh1, wi1, wi0, whd, bs0, bs1, bhd);

  const int ngemm = Tc * 8;
  for (int L = 0; L < nch + 2; ++L) {
    Params P;
    P.x = x;
    P.wh0 = wh0; P.wh1 = wh1; P.wi0 = wi0; P.wi1 = wi1; P.whd = whd;
    P.bs0 = bs0; P.bs1 = bs1; P.bhd = bhd;
    P.h0s = h0s; P.c0s = c0s; P.h1s = h1s; P.c1s = c1s;
    P.h1w = h1buf[L & 1];
    P.h1r = h1buf[(L + 1) & 1];
    P.xww = xwbuf[(L + 1) & 1];
    P.xwr = xwbuf[L & 1];
    P.y = y;
    P.L = L; P.Tc = Tc; P.nch = nch;
    if (L & 1)
      fused_kernel<1><<<128 + ngemm, 512, 0, stream>>>(P);
    else
      fused_kernel<0><<<128 + ngemm, 512, 0, stream>>>(P);
  }
}

// Round 8
// 9770.292 us; speedup vs baseline: 9.8016x; 9.8016x over previous
//
#include <hip/hip_runtime.h>
#include <hip/hip_fp16.h>
#include <stdint.h>

// ---------------------------------------------------------------------------
// SequentialEMGPoseLSTM: 2-layer LSTM (H=256, B=64, T=4096) + LeakyReLU+Linear
//
// R10 = R3 (best measured: 9.87ms total, 577us steady) + ONE verified delta.
// Post-mortem R9: the fma_mix A/B instantiation spilled on its own (compiler
// materializes f32-converted weight copies -> 8.8GB scratch traffic) — the
// fma_mix source path is dead regardless of ISA rates. The dot2+STEP_BARRIER
// even-L dispatches were NOT in the top-5 (i.e. R3-class). Two failed probe
// rounds: revert to proven base, keep probes out of the shipping kernel.
//  - Single delta vs R3: end-of-step __syncthreads() -> lgkm-only barrier
//    (asm "s_waitcnt lgkmcnt(0); s_barrier"). Removes the per-step
//    s_waitcnt vmcnt(0) drain of the in-flight h1w stores / xw loads / y
//    stores. Numerics-safe: LDS ordering (hbuf/abuf) is fully covered by
//    lgkmcnt(0)+barrier; global stores are consumed only by the NEXT
//    dispatch (kernel-end drain); xw loads get compiler-inserted precise
//    vmcnt waits before use. Scheme validated bit-exact in R7.
//  - Everything else is R3 verbatim (512 thr, 2 waves/SIMD, quad_sum DPP,
//    owner slices 0/1, 4096-block one-tile MFMA GEMM, fp32 xw buffers).
// ---------------------------------------------------------------------------

#define T_SEQ 4096
#define NB    64
#define HID   256
#define G4    1024
#define INCH  16
#define OC    20

typedef _Float16 h2v   __attribute__((ext_vector_type(2)));
typedef _Float16 f16x8 __attribute__((ext_vector_type(8)));
typedef float    f32x4 __attribute__((ext_vector_type(4)));

__device__ __forceinline__ float fdot2(uint32_t a, uint32_t b, float c) {
  return __builtin_amdgcn_fdot2(__builtin_bit_cast(h2v, a),
                                __builtin_bit_cast(h2v, b), c, false);
}
__device__ __forceinline__ float sigf(float x) {
  x = fminf(fmaxf(x, -30.f), 30.f);
  return 1.f / (1.f + __expf(-x));
}
__device__ __forceinline__ float tanhf_fast(float x) {
  x = fminf(fmaxf(x, -15.f), 15.f);
  float e = __expf(-2.f * x);
  return (1.f - e) / (1.f + e);
}
// Sum across the 4 slices of a quad (lanes differing in bits 0-1) on the
// VALU pipe: quad_perm(1,0,3,2)=0xB1 then quad_perm(2,3,0,1)=0x4E.
__device__ __forceinline__ float quad_sum(float a) {
  a += __int_as_float(
      __builtin_amdgcn_update_dpp(0, __float_as_int(a), 0xB1, 0xF, 0xF, true));
  a += __int_as_float(
      __builtin_amdgcn_update_dpp(0, __float_as_int(a), 0x4E, 0xF, 0xF, true));
  return a;
}

#define PIN(x) asm volatile("" : "+v"(x))
// LDS-only step barrier: no vmcnt drain (R7-verified numerics-safe).
#define STEP_BARRIER() asm volatile("s_waitcnt lgkmcnt(0)\n\ts_barrier" ::: "memory")

// Padded LDS layouts (all offsets 16B-aligned):
//  w   : 256 rows x 264 halves (rows 768..1023 of Whh). Row r at bank 4r%32.
//  hbuf: 2 x (4 slices x 72 halves). Slice s at bank offset 4s -> disjoint spans.
//  abuf: 2 x (8 chunks x 40 halves). Chunk ks at bank 20ks%32 -> all distinct.
struct SmemR {
  __half w[256 * 264];        // 135168 B
  uint32_t hbuf[2][144];      // 1152 B
  float bsum[1024];           // 4096 B
  union {
    uint32_t xb[512 * 8];     // layer0: packed x pairs [tt][dp], Tc<=512
    struct {
      __half abuf[2][320];    // layer1: leaky(h2), padded chunks
      __half whd[20 * 264];   // head weights, padded rows
      float  bh[20];
    } h1;
  } u;
};
struct SmemG {
  __half a[128 * 40];
  __half b[64 * 40];
};
union Smem { SmemR r; SmemG g; };

struct Params {
  const float* x;
  const __half *wh0, *wh1, *wi0, *wi1, *whd;
  const float  *bs0, *bs1, *bhd;
  float *h0s, *c0s, *h1s, *c1s;
  __half* h1w; const __half* h1r;
  float* xww;  const float* xwr;
  float* y;
  int L, Tc, nch;
};

// ---------------------------------------------------------------------------
// Recurrent role: one block == one batch chain. 512 threads.
// slice = tid&3 covers k in [64*slice, 64*slice+64); rg = tid>>2 (0..127).
// Thread handles gate rows r = rg + 128*j, j=0..7 (j<6 reg, j>=6 LDS).
// Row rg+128j: j even -> gate (j/2) of channel rg; j odd -> of channel rg+128.
// Owners: slice0 -> channel rg, slice1 -> channel rg+128.
// ---------------------------------------------------------------------------
template <int LAYER>
__device__ void role_rec(SmemR& S, int ch, const Params& P, int b) {
  if (ch < 0 || ch >= P.nch) return;
  const int tid   = threadIdx.x;
  const int slice = tid & 3;
  const int rg    = tid >> 2;
  const int Tc    = P.Tc;
  const __half* whh = (LAYER == 0) ? P.wh0 : P.wh1;

  // Stage LDS-resident weight rows 768..1023 into padded layout.
  for (int i = tid; i < 8192; i += 512) {
    int R = i >> 5, oct = i & 31;
    *(uint4*)&S.w[R * 264 + oct * 8] =
        *((const uint4*)(whh + (768 + R) * 256) + oct);
  }
  {
    const float* bs = (LAYER == 0) ? P.bs0 : P.bs1;
    for (int i = tid; i < 1024; i += 512) S.bsum[i] = bs[i];
  }
  const int t0 = ch * Tc;
  if (LAYER == 0) {
    for (int i = tid; i < Tc * 8; i += 512) {
      int dp = i / Tc, tt = i - dp * Tc;
      float v0 = P.x[(b * INCH + 2 * dp) * T_SEQ + t0 + tt];
      float v1 = P.x[(b * INCH + 2 * dp + 1) * T_SEQ + t0 + tt];
      uint32_t pv = (uint32_t)__half_as_ushort(__float2half(v0)) |
                    ((uint32_t)__half_as_ushort(__float2half(v1)) << 16);
      S.u.xb[tt * 8 + dp] = pv;
    }
  } else {
    for (int i = tid; i < OC * 256; i += 512) {
      int o = i >> 8, k = i & 255;
      S.u.h1.whd[o * 264 + k] = P.whd[i];
    }
    if (tid < OC) S.u.h1.bh[tid] = P.bhd[tid];
  }

  // Register-resident weights: rows j=0..5, 64 halves each (32 packed u32).
  uint32_t wr[6][32];
#pragma unroll
  for (int j = 0; j < 6; j++) {
    const uint4* p = (const uint4*)(whh + (rg + 128 * j) * 256 + slice * 64);
#pragma unroll
    for (int q = 0; q < 8; q++) {
      uint4 v = p[q];
      wr[j][4 * q] = v.x; wr[j][4 * q + 1] = v.y;
      wr[j][4 * q + 2] = v.z; wr[j][4 * q + 3] = v.w;
    }
  }
#pragma unroll
  for (int j = 0; j < 6; j++)
#pragma unroll
    for (int q = 0; q < 32; q++) PIN(wr[j][q]);

  uint32_t wx[8][2];
  if (LAYER == 0) {
#pragma unroll
    for (int j = 0; j < 8; j++) {
      const uint32_t* p = (const uint32_t*)(P.wi0 + (rg + 128 * j) * INCH + slice * 4);
      wx[j][0] = p[0]; wx[j][1] = p[1];
    }
#pragma unroll
    for (int j = 0; j < 8; j++) { PIN(wx[j][0]); PIN(wx[j][1]); }
  }

  // State: slice-0/1 threads own channels rg / rg+128 (fp32 h,c).
  const bool own = (slice < 2);
  const int chn = rg + ((slice & 1) << 7);
  float* hs = (LAYER == 0) ? P.h0s : P.h1s;
  float* cs = (LAYER == 0) ? P.c0s : P.c1s;
  float hO = 0.f, cO = 0.f;
  if (own) {
    if (ch != 0) { hO = hs[b * 256 + chn]; cO = cs[b * 256 + chn]; }
    ((__half*)S.hbuf[0])[(chn >> 6) * 72 + (chn & 63)] = __float2half(hO);
  }
  const float* xp = (LAYER == 1 && own) ? (P.xwr + (size_t)b * G4 + chn)
                                        : (const float*)nullptr;
  __syncthreads();

  const __half* hbA = (const __half*)S.hbuf[0] + slice * 72;
  const __half* hbB = (const __half*)S.hbuf[1] + slice * 72;
  __half hprev = __float2half(0.f);
  float xwv[4] = {0.f, 0.f, 0.f, 0.f};

  for (int tt = 0; tt < Tc; ++tt) {
    // ---- post-barrier zone: global ops retire under this step's compute
    // (the lgkm-only step barrier never drains them).
    if (LAYER == 0 && own && tt > 0)
      P.h1w[(size_t)((tt - 1) * NB + b) * 256 + chn] = hprev;
    if (LAYER == 1 && own) {
      const float* q = xp + (size_t)tt * (NB * G4);
      xwv[0] = q[0]; xwv[1] = q[256]; xwv[2] = q[512]; xwv[3] = q[768];
    }

    const __half* hb = (tt & 1) ? hbB : hbA;
    float acc[8];
#pragma unroll
    for (int j = 0; j < 8; j++) acc[j] = 0.f;

#pragma unroll
    for (int hf = 0; hf < 2; ++hf) {
      uint32_t hh[16];
      const uint4* hp = (const uint4*)(hb + hf * 32);
#pragma unroll
      for (int q = 0; q < 4; q++) {
        uint4 v = hp[q];
        hh[4 * q] = v.x; hh[4 * q + 1] = v.y; hh[4 * q + 2] = v.z; hh[4 * q + 3] = v.w;
      }
#pragma unroll
      for (int j = 0; j < 6; j++) {
        float a = acc[j];
#pragma unroll
        for (int q = 0; q < 16; q++) a = fdot2(wr[j][hf * 16 + q], hh[q], a);
        acc[j] = a;
      }
#pragma unroll
      for (int j = 6; j < 8; j++) {
        const uint4* wp =
            (const uint4*)&S.w[((j - 6) * 128 + rg) * 264 + slice * 64 + hf * 32];
        float a = acc[j];
#pragma unroll
        for (int q = 0; q < 4; q++) {
          uint4 v = wp[q];
          a = fdot2(v.x, hh[4 * q], a);
          a = fdot2(v.y, hh[4 * q + 1], a);
          a = fdot2(v.z, hh[4 * q + 2], a);
          a = fdot2(v.w, hh[4 * q + 3], a);
        }
        acc[j] = a;
      }
    }
    if (LAYER == 0) {
      uint32_t xv0 = S.u.xb[tt * 8 + 2 * slice];
      uint32_t xv1 = S.u.xb[tt * 8 + 2 * slice + 1];
#pragma unroll
      for (int j = 0; j < 8; j++) {
        acc[j] = fdot2(wx[j][0], xv0, acc[j]);
        acc[j] = fdot2(wx[j][1], xv1, acc[j]);
      }
    }
#pragma unroll
    for (int j = 0; j < 8; j++) acc[j] = quad_sum(acc[j]);

    if (own) {
      const int o = slice & 1;  // 0 -> channel rg (even j), 1 -> rg+128 (odd j)
      float gi = acc[0 + o] + S.bsum[chn];
      float gf = acc[2 + o] + S.bsum[chn + 256];
      float gg = acc[4 + o] + S.bsum[chn + 512];
      float go = acc[6 + o] + S.bsum[chn + 768];
      if (LAYER == 1) { gi += xwv[0]; gf += xwv[1]; gg += xwv[2]; go += xwv[3]; }
      float iv = sigf(gi), fv = sigf(gf);
      float gv = tanhf_fast(gg), ov = sigf(go);
      cO = fv * cO + iv * gv;
      hO = ov * tanhf_fast(cO);
      __half h16 = __float2half(hO);
      ((__half*)S.hbuf[(tt + 1) & 1])[(chn >> 6) * 72 + (chn & 63)] = h16;
      if (LAYER == 0) {
        hprev = h16;  // stored at top of next iteration (post-barrier)
      } else {
        float av = hO > 0.f ? hO : 0.01f * hO;
        S.u.h1.abuf[tt & 1][(chn >> 5) * 40 + (chn & 31)] = __float2half(av);
      }
    }
    STEP_BARRIER();  // lgkmcnt(0)+s_barrier only; no vmcnt drain (R10 delta)

    // Head (layer1): 20 outputs x 8 lanes x 32 k. Reads abuf[tt&1] written
    // before the barrier; next overwrite of that buffer is 2 steps away and
    // gated by the intervening barrier. y-store floats into the next step.
    if (LAYER == 1 && tid < OC * 8) {
      int o = tid >> 3, ks = tid & 7;
      const uint4* wp = (const uint4*)&S.u.h1.whd[o * 264 + ks * 32];
      const uint4* ap = (const uint4*)&S.u.h1.abuf[tt & 1][ks * 40];
      float a = 0.f;
#pragma unroll
      for (int q = 0; q < 4; q++) {
        uint4 w4 = wp[q];
        uint4 a4 = ap[q];
        a = fdot2(w4.x, a4.x, a);
        a = fdot2(w4.y, a4.y, a);
        a = fdot2(w4.z, a4.z, a);
        a = fdot2(w4.w, a4.w, a);
      }
      a += __shfl_xor(a, 1);
      a += __shfl_xor(a, 2);
      a += __shfl_xor(a, 4);
      if (ks == 0) P.y[(b * OC + o) * T_SEQ + t0 + tt] = a + S.u.h1.bh[o];
    }
  }
  if (own) {
    if (LAYER == 0)
      P.h1w[(size_t)((Tc - 1) * NB + b) * 256 + chn] = hprev;
    hs[b * 256 + chn] = hO;
    cs[b * 256 + chn] = cO;
  }
}

// ---------------------------------------------------------------------------
// GEMM role: xw1[tb, g] = sum_k h1[tb,k] * Wih1[g,k], f16 MFMA, fp32 out.
// R3's proven grid: one 128x64 tile per block, Tc*8 blocks.
// ---------------------------------------------------------------------------
__device__ void role_gemm(SmemG& S, int chG, const Params& P) {
  if (chG < 0 || chG >= P.nch) return;
  const int bid = blockIdx.x - 128;
  const int nt = bid & 15, mt = bid >> 4;
  const int tb0 = mt * 128, g0 = nt * 64;
  const int tid = threadIdx.x, lane = tid & 63, w = tid >> 6;
  const int wm = w & 3, wn = w >> 2;

  f32x4 cacc[2][2] = {};
  for (int kk = 0; kk < 256; kk += 32) {
    __syncthreads();
    {
      int row = tid >> 2, q = tid & 3;
      const uint4* src = (const uint4*)(P.h1r + (tb0 + row) * 256 + kk + q * 8);
      *(uint4*)&S.a[row * 40 + q * 8] = *src;
    }
    if (tid < 256) {
      int row = tid >> 2, q = tid & 3;
      const uint4* src = (const uint4*)(P.wi1 + (g0 + row) * 256 + kk + q * 8);
      *(uint4*)&S.b[row * 40 + q * 8] = *src;
    }
    __syncthreads();
    f16x8 af[2], bf[2];
#pragma unroll
    for (int mi = 0; mi < 2; mi++)
      af[mi] = *(const f16x8*)&S.a[(wm * 32 + mi * 16 + (lane & 15)) * 40 + (lane >> 4) * 8];
#pragma unroll
    for (int ni = 0; ni < 2; ni++)
      bf[ni] = *(const f16x8*)&S.b[(wn * 32 + ni * 16 + (lane & 15)) * 40 + (lane >> 4) * 8];
#pragma unroll
    for (int mi = 0; mi < 2; mi++)
#pragma unroll
      for (int ni = 0; ni < 2; ni++)
        cacc[mi][ni] = __builtin_amdgcn_mfma_f32_16x16x32_f16(af[mi], bf[ni], cacc[mi][ni], 0, 0, 0);
  }
#pragma unroll
  for (int mi = 0; mi < 2; mi++)
#pragma unroll
    for (int ni = 0; ni < 2; ni++) {
      int m = wm * 32 + mi * 16 + (lane >> 4) * 4;
      int n = g0 + wn * 32 + ni * 16 + (lane & 15);
#pragma unroll
      for (int r = 0; r < 4; r++)
        P.xww[(size_t)(tb0 + m + r) * G4 + n] = cacc[mi][ni][r];
    }
}

__global__ __launch_bounds__(512)
__attribute__((amdgpu_waves_per_eu(2, 2)))
void fused_kernel(Params P) {
  __shared__ Smem S;
  int bid = blockIdx.x;
  if (bid < 64)        role_rec<0>(S.r, P.L, P, bid);
  else if (bid < 128)  role_rec<1>(S.r, P.L - 2, P, bid - 64);
  else                 role_gemm(S.g, P.L - 1, P);
}

// ---------------------------------------------------------------------------
__global__ void prep_kernel(const float* Wih0, const float* Whh0,
                            const float* bih0, const float* bhh0,
                            const float* Wih1, const float* Whh1,
                            const float* bih1, const float* bhh1,
                            const float* Whead, const float* bhead,
                            __half* wh0, __half* wh1, __half* wi1, __half* wi0,
                            __half* whd, float* bs0, float* bs1, float* bhd) {
  int i = blockIdx.x * blockDim.x + threadIdx.x;
  if (i < G4 * HID) {
    wh0[i] = __float2half(Whh0[i]);
    wh1[i] = __float2half(Whh1[i]);
    wi1[i] = __float2half(Wih1[i]);
  }
  if (i < G4 * INCH) wi0[i] = __float2half(Wih0[i]);
  if (i < OC * HID)  whd[i] = __float2half(Whead[i]);
  if (i < G4) { bs0[i] = bih0[i] + bhh0[i]; bs1[i] = bih1[i] + bhh1[i]; }
  if (i < OC) bhd[i] = bhead[i];
}

// ---------------------------------------------------------------------------
extern "C" void kernel_launch(void* const* d_in, const int* in_sizes, int n_in,
                              void* d_out, int out_size, void* d_ws, size_t ws_size,
                              hipStream_t stream) {
  const float* x     = (const float*)d_in[0];
  const float* Wih0  = (const float*)d_in[1];
  const float* Whh0  = (const float*)d_in[2];
  const float* bih0  = (const float*)d_in[3];
  const float* bhh0  = (const float*)d_in[4];
  const float* Wih1  = (const float*)d_in[5];
  const float* Whh1  = (const float*)d_in[6];
  const float* bih1  = (const float*)d_in[7];
  const float* bhh1  = (const float*)d_in[8];
  const float* Whead = (const float*)d_in[9];
  const float* bhead = (const float*)d_in[10];
  float* y = (float*)d_out;

  char* ws = (char*)d_ws;
  size_t cur = 0;
  auto alloc = [&](size_t sz) -> char* {
    char* p = ws + cur;
    cur = (cur + sz + 255) & ~(size_t)255;
    return p;
  };
  __half* wh0 = (__half*)alloc(G4 * HID * 2);
  __half* wh1 = (__half*)alloc(G4 * HID * 2);
  __half* wi1 = (__half*)alloc(G4 * HID * 2);
  __half* wi0 = (__half*)alloc(G4 * INCH * 2);
  __half* whd = (__half*)alloc(OC * HID * 2);
  float* bs0 = (float*)alloc(G4 * 4);
  float* bs1 = (float*)alloc(G4 * 4);
  float* bhd = (float*)alloc(OC * 4);
  float* h0s = (float*)alloc(NB * HID * 4);
  float* c0s = (float*)alloc(NB * HID * 4);
  float* h1s = (float*)alloc(NB * HID * 4);
  float* c1s = (float*)alloc(NB * HID * 4);
  size_t fixed = cur;

  int Tc = 512;
  while (Tc > 64) {
    size_t need = fixed + 2 * ((size_t)Tc * NB * HID * 2 + 512) +
                  2 * ((size_t)Tc * NB * G4 * 4 + 512);
    if (need <= ws_size) break;
    Tc >>= 1;
  }
  __half* h1buf[2];
  float* xwbuf[2];
  h1buf[0] = (__half*)alloc((size_t)Tc * NB * HID * 2);
  h1buf[1] = (__half*)alloc((size_t)Tc * NB * HID * 2);
  xwbuf[0] = (float*)alloc((size_t)Tc * NB * G4 * 4);
  xwbuf[1] = (float*)alloc((size_t)Tc * NB * G4 * 4);

  const int nch = T_SEQ / Tc;

  prep_kernel<<<(G4 * HID + 255) / 256, 256, 0, stream>>>(
      Wih0, Whh0, bih0, bhh0, Wih1, Whh1, bih1, bhh1, Whead, bhead,
      wh0, wh1, wi1, wi0, whd, bs0, bs1, bhd);

  const int ngemm = Tc * 8;
  for (int L = 0; L < nch + 2; ++L) {
    Params P;
    P.x = x;
    P.wh0 = wh0; P.wh1 = wh1; P.wi0 = wi0; P.wi1 = wi1; P.whd = whd;
    P.bs0 = bs0; P.bs1 = bs1; P.bhd = bhd;
    P.h0s = h0s; P.c0s = c0s; P.h1s = h1s; P.c1s = c1s;
    P.h1w = h1buf[L & 1];
    P.h1r = h1buf[(L + 1) & 1];
    P.xww = xwbuf[(L + 1) & 1];
    P.xwr = xwbuf[L & 1];
    P.y = y;
    P.L = L; P.Tc = Tc; P.nch = nch;
    fused_kernel<<<128 + ngemm, 512, 0, stream>>>(P);
  }
}

// Round 9
// 9662.943 us; speedup vs baseline: 9.9105x; 1.0111x over previous
//
#include <hip/hip_runtime.h>
#include <hip/hip_fp16.h>
#include <stdint.h>

// ---------------------------------------------------------------------------
// SequentialEMGPoseLSTM: 2-layer LSTM (H=256, B=64, T=4096) + LeakyReLU+Linear
//
// R11 = R10 (proven: 9.77ms total, 570us steady, bit-exact) + pipeline-
// geometry deltas. Post-mortem R10: lgkm-only barrier = +1% -> the per-step
// vmcnt drain was already hidden; step wall ~5350cyc is pipe-bound
// (VALU ~3600 + LDS ~1500 with imperfect overlap); the 3.66e7 "bank
// conflicts" decompose to ~7 extra phases per wave64 b128 read = inherent
// multi-phase serialization, not a fixable layout problem. Step time is at
// this decomposition's floor; total time still has a non-step term:
//  - Tc: 256 -> 128. Total = (T + 2*Tc)*t_step + per-dispatch overhead;
//    halving Tc removes 256 pipeline-bubble steps (~540us) for ~16 extra
//    prologues/launches (~180us). Bonus: xw working set (2x33MB fp32) now
//    L3-resident -> xw reads stop missing to HBM (watch FETCH_SIZE).
//  - bias sums restored to registers (R3 detail lost in R10's revert):
//    kills 4 per-step LDS reads/owner + the 4KB bsum staging pass.
// ---------------------------------------------------------------------------

#define T_SEQ 4096
#define NB    64
#define HID   256
#define G4    1024
#define INCH  16
#define OC    20

typedef _Float16 h2v   __attribute__((ext_vector_type(2)));
typedef _Float16 f16x8 __attribute__((ext_vector_type(8)));
typedef float    f32x4 __attribute__((ext_vector_type(4)));

__device__ __forceinline__ float fdot2(uint32_t a, uint32_t b, float c) {
  return __builtin_amdgcn_fdot2(__builtin_bit_cast(h2v, a),
                                __builtin_bit_cast(h2v, b), c, false);
}
__device__ __forceinline__ float sigf(float x) {
  x = fminf(fmaxf(x, -30.f), 30.f);
  return 1.f / (1.f + __expf(-x));
}
__device__ __forceinline__ float tanhf_fast(float x) {
  x = fminf(fmaxf(x, -15.f), 15.f);
  float e = __expf(-2.f * x);
  return (1.f - e) / (1.f + e);
}
// Sum across the 4 slices of a quad (lanes differing in bits 0-1) on the
// VALU pipe: quad_perm(1,0,3,2)=0xB1 then quad_perm(2,3,0,1)=0x4E.
__device__ __forceinline__ float quad_sum(float a) {
  a += __int_as_float(
      __builtin_amdgcn_update_dpp(0, __float_as_int(a), 0xB1, 0xF, 0xF, true));
  a += __int_as_float(
      __builtin_amdgcn_update_dpp(0, __float_as_int(a), 0x4E, 0xF, 0xF, true));
  return a;
}

#define PIN(x) asm volatile("" : "+v"(x))
// LDS-only step barrier: no vmcnt drain (R7/R10-verified numerics-safe).
#define STEP_BARRIER() asm volatile("s_waitcnt lgkmcnt(0)\n\ts_barrier" ::: "memory")

// Padded LDS layouts (all offsets 16B-aligned):
//  w   : 256 rows x 264 halves (rows 768..1023 of Whh). Row r at bank 4r%32.
//  hbuf: 2 x (4 slices x 72 halves). Slice s at bank offset 4s -> disjoint spans.
//  abuf: 2 x (8 chunks x 40 halves). Chunk ks at bank 20ks%32 -> all distinct.
struct SmemR {
  __half w[256 * 264];        // 135168 B
  uint32_t hbuf[2][144];      // 1152 B
  union {
    uint32_t xb[512 * 8];     // layer0: packed x pairs [tt][dp], Tc<=512
    struct {
      __half abuf[2][320];    // layer1: leaky(h2), padded chunks
      __half whd[20 * 264];   // head weights, padded rows
      float  bh[20];
    } h1;
  } u;
};
struct SmemG {
  __half a[128 * 40];
  __half b[64 * 40];
};
union Smem { SmemR r; SmemG g; };

struct Params {
  const float* x;
  const __half *wh0, *wh1, *wi0, *wi1, *whd;
  const float  *bs0, *bs1, *bhd;
  float *h0s, *c0s, *h1s, *c1s;
  __half* h1w; const __half* h1r;
  float* xww;  const float* xwr;
  float* y;
  int L, Tc, nch;
};

// ---------------------------------------------------------------------------
// Recurrent role: one block == one batch chain. 512 threads.
// slice = tid&3 covers k in [64*slice, 64*slice+64); rg = tid>>2 (0..127).
// Thread handles gate rows r = rg + 128*j, j=0..7 (j<6 reg, j>=6 LDS).
// Row rg+128j: j even -> gate (j/2) of channel rg; j odd -> of channel rg+128.
// Owners: slice0 -> channel rg, slice1 -> channel rg+128.
// ---------------------------------------------------------------------------
template <int LAYER>
__device__ void role_rec(SmemR& S, int ch, const Params& P, int b) {
  if (ch < 0 || ch >= P.nch) return;
  const int tid   = threadIdx.x;
  const int slice = tid & 3;
  const int rg    = tid >> 2;
  const int Tc    = P.Tc;
  const __half* whh = (LAYER == 0) ? P.wh0 : P.wh1;

  // Stage LDS-resident weight rows 768..1023 into padded layout.
  for (int i = tid; i < 8192; i += 512) {
    int R = i >> 5, oct = i & 31;
    *(uint4*)&S.w[R * 264 + oct * 8] =
        *((const uint4*)(whh + (768 + R) * 256) + oct);
  }
  const int t0 = ch * Tc;
  if (LAYER == 0) {
    for (int i = tid; i < Tc * 8; i += 512) {
      int dp = i / Tc, tt = i - dp * Tc;
      float v0 = P.x[(b * INCH + 2 * dp) * T_SEQ + t0 + tt];
      float v1 = P.x[(b * INCH + 2 * dp + 1) * T_SEQ + t0 + tt];
      uint32_t pv = (uint32_t)__half_as_ushort(__float2half(v0)) |
                    ((uint32_t)__half_as_ushort(__float2half(v1)) << 16);
      S.u.xb[tt * 8 + dp] = pv;
    }
  } else {
    for (int i = tid; i < OC * 256; i += 512) {
      int o = i >> 8, k = i & 255;
      S.u.h1.whd[o * 264 + k] = P.whd[i];
    }
    if (tid < OC) S.u.h1.bh[tid] = P.bhd[tid];
  }

  // Register-resident weights: rows j=0..5, 64 halves each (32 packed u32).
  uint32_t wr[6][32];
#pragma unroll
  for (int j = 0; j < 6; j++) {
    const uint4* p = (const uint4*)(whh + (rg + 128 * j) * 256 + slice * 64);
#pragma unroll
    for (int q = 0; q < 8; q++) {
      uint4 v = p[q];
      wr[j][4 * q] = v.x; wr[j][4 * q + 1] = v.y;
      wr[j][4 * q + 2] = v.z; wr[j][4 * q + 3] = v.w;
    }
  }
#pragma unroll
  for (int j = 0; j < 6; j++)
#pragma unroll
    for (int q = 0; q < 32; q++) PIN(wr[j][q]);

  uint32_t wx[8][2];
  if (LAYER == 0) {
#pragma unroll
    for (int j = 0; j < 8; j++) {
      const uint32_t* p = (const uint32_t*)(P.wi0 + (rg + 128 * j) * INCH + slice * 4);
      wx[j][0] = p[0]; wx[j][1] = p[1];
    }
#pragma unroll
    for (int j = 0; j < 8; j++) { PIN(wx[j][0]); PIN(wx[j][1]); }
  }

  // Owner state: slice0 -> channel rg; slice1 -> channel rg+128 (fp32 h,c).
  // Bias sums live in registers (bs4), not LDS (R3 detail restored).
  const bool own = (slice < 2);
  const int chn = rg + ((slice & 1) << 7);
  float* hs = (LAYER == 0) ? P.h0s : P.h1s;
  float* cs = (LAYER == 0) ? P.c0s : P.c1s;
  float bs4[4] = {0.f, 0.f, 0.f, 0.f};
  float hO = 0.f, cO = 0.f;
  if (own) {
    const float* bsg = (LAYER == 0) ? P.bs0 : P.bs1;
#pragma unroll
    for (int k = 0; k < 4; k++) bs4[k] = bsg[chn + 256 * k];
    if (ch != 0) { hO = hs[b * 256 + chn]; cO = cs[b * 256 + chn]; }
    ((__half*)S.hbuf[0])[(chn >> 6) * 72 + (chn & 63)] = __float2half(hO);
  }
  const float* xp = (LAYER == 1 && own) ? (P.xwr + (size_t)b * G4 + chn)
                                        : (const float*)nullptr;
  __syncthreads();

  const __half* hbA = (const __half*)S.hbuf[0] + slice * 72;
  const __half* hbB = (const __half*)S.hbuf[1] + slice * 72;
  __half hprev = __float2half(0.f);
  float xwv[4] = {0.f, 0.f, 0.f, 0.f};

  for (int tt = 0; tt < Tc; ++tt) {
    // ---- post-barrier zone: global ops retire under this step's compute
    // (the lgkm-only step barrier never drains them).
    if (LAYER == 0 && own && tt > 0)
      P.h1w[(size_t)((tt - 1) * NB + b) * 256 + chn] = hprev;
    if (LAYER == 1 && own) {
      const float* q = xp + (size_t)tt * (NB * G4);
      xwv[0] = q[0]; xwv[1] = q[256]; xwv[2] = q[512]; xwv[3] = q[768];
    }

    const __half* hb = (tt & 1) ? hbB : hbA;
    float acc[8];
#pragma unroll
    for (int j = 0; j < 8; j++) acc[j] = 0.f;

#pragma unroll
    for (int hf = 0; hf < 2; ++hf) {
      uint32_t hh[16];
      const uint4* hp = (const uint4*)(hb + hf * 32);
#pragma unroll
      for (int q = 0; q < 4; q++) {
        uint4 v = hp[q];
        hh[4 * q] = v.x; hh[4 * q + 1] = v.y; hh[4 * q + 2] = v.z; hh[4 * q + 3] = v.w;
      }
#pragma unroll
      for (int j = 0; j < 6; j++) {
        float a = acc[j];
#pragma unroll
        for (int q = 0; q < 16; q++) a = fdot2(wr[j][hf * 16 + q], hh[q], a);
        acc[j] = a;
      }
#pragma unroll
      for (int j = 6; j < 8; j++) {
        const uint4* wp =
            (const uint4*)&S.w[((j - 6) * 128 + rg) * 264 + slice * 64 + hf * 32];
        float a = acc[j];
#pragma unroll
        for (int q = 0; q < 4; q++) {
          uint4 v = wp[q];
          a = fdot2(v.x, hh[4 * q], a);
          a = fdot2(v.y, hh[4 * q + 1], a);
          a = fdot2(v.z, hh[4 * q + 2], a);
          a = fdot2(v.w, hh[4 * q + 3], a);
        }
        acc[j] = a;
      }
    }
    if (LAYER == 0) {
      uint32_t xv0 = S.u.xb[tt * 8 + 2 * slice];
      uint32_t xv1 = S.u.xb[tt * 8 + 2 * slice + 1];
#pragma unroll
      for (int j = 0; j < 8; j++) {
        acc[j] = fdot2(wx[j][0], xv0, acc[j]);
        acc[j] = fdot2(wx[j][1], xv1, acc[j]);
      }
    }
#pragma unroll
    for (int j = 0; j < 8; j++) acc[j] = quad_sum(acc[j]);

    if (own) {
      const int o = slice & 1;  // 0 -> channel rg (even j), 1 -> rg+128 (odd j)
      float gi = acc[0 + o] + bs4[0];
      float gf = acc[2 + o] + bs4[1];
      float gg = acc[4 + o] + bs4[2];
      float go = acc[6 + o] + bs4[3];
      if (LAYER == 1) { gi += xwv[0]; gf += xwv[1]; gg += xwv[2]; go += xwv[3]; }
      float iv = sigf(gi), fv = sigf(gf);
      float gv = tanhf_fast(gg), ov = sigf(go);
      cO = fv * cO + iv * gv;
      hO = ov * tanhf_fast(cO);
      __half h16 = __float2half(hO);
      ((__half*)S.hbuf[(tt + 1) & 1])[(chn >> 6) * 72 + (chn & 63)] = h16;
      if (LAYER == 0) {
        hprev = h16;  // stored at top of next iteration (post-barrier)
      } else {
        float av = hO > 0.f ? hO : 0.01f * hO;
        S.u.h1.abuf[tt & 1][(chn >> 5) * 40 + (chn & 31)] = __float2half(av);
      }
    }
    STEP_BARRIER();  // lgkmcnt(0)+s_barrier only; no vmcnt drain

    // Head (layer1): 20 outputs x 8 lanes x 32 k. Reads abuf[tt&1] written
    // before the barrier; next overwrite of that buffer is 2 steps away and
    // gated by the intervening barrier. y-store floats into the next step.
    if (LAYER == 1 && tid < OC * 8) {
      int o = tid >> 3, ks = tid & 7;
      const uint4* wp = (const uint4*)&S.u.h1.whd[o * 264 + ks * 32];
      const uint4* ap = (const uint4*)&S.u.h1.abuf[tt & 1][ks * 40];
      float a = 0.f;
#pragma unroll
      for (int q = 0; q < 4; q++) {
        uint4 w4 = wp[q];
        uint4 a4 = ap[q];
        a = fdot2(w4.x, a4.x, a);
        a = fdot2(w4.y, a4.y, a);
        a = fdot2(w4.z, a4.z, a);
        a = fdot2(w4.w, a4.w, a);
      }
      a += __shfl_xor(a, 1);
      a += __shfl_xor(a, 2);
      a += __shfl_xor(a, 4);
      if (ks == 0) P.y[(b * OC + o) * T_SEQ + t0 + tt] = a + S.u.h1.bh[o];
    }
  }
  if (own) {
    if (LAYER == 0)
      P.h1w[(size_t)((Tc - 1) * NB + b) * 256 + chn] = hprev;
    hs[b * 256 + chn] = hO;
    cs[b * 256 + chn] = cO;
  }
}

// ---------------------------------------------------------------------------
// GEMM role: xw1[tb, g] = sum_k h1[tb,k] * Wih1[g,k], f16 MFMA, fp32 out.
// R3's proven grid: one 128x64 tile per block, Tc*8 blocks.
// ---------------------------------------------------------------------------
__device__ void role_gemm(SmemG& S, int chG, const Params& P) {
  if (chG < 0 || chG >= P.nch) return;
  const int bid = blockIdx.x - 128;
  const int nt = bid & 15, mt = bid >> 4;
  const int tb0 = mt * 128, g0 = nt * 64;
  const int tid = threadIdx.x, lane = tid & 63, w = tid >> 6;
  const int wm = w & 3, wn = w >> 2;

  f32x4 cacc[2][2] = {};
  for (int kk = 0; kk < 256; kk += 32) {
    __syncthreads();
    {
      int row = tid >> 2, q = tid & 3;
      const uint4* src = (const uint4*)(P.h1r + (tb0 + row) * 256 + kk + q * 8);
      *(uint4*)&S.a[row * 40 + q * 8] = *src;
    }
    if (tid < 256) {
      int row = tid >> 2, q = tid & 3;
      const uint4* src = (const uint4*)(P.wi1 + (g0 + row) * 256 + kk + q * 8);
      *(uint4*)&S.b[row * 40 + q * 8] = *src;
    }
    __syncthreads();
    f16x8 af[2], bf[2];
#pragma unroll
    for (int mi = 0; mi < 2; mi++)
      af[mi] = *(const f16x8*)&S.a[(wm * 32 + mi * 16 + (lane & 15)) * 40 + (lane >> 4) * 8];
#pragma unroll
    for (int ni = 0; ni < 2; ni++)
      bf[ni] = *(const f16x8*)&S.b[(wn * 32 + ni * 16 + (lane & 15)) * 40 + (lane >> 4) * 8];
#pragma unroll
    for (int mi = 0; mi < 2; mi++)
#pragma unroll
      for (int ni = 0; ni < 2; ni++)
        cacc[mi][ni] = __builtin_amdgcn_mfma_f32_16x16x32_f16(af[mi], bf[ni], cacc[mi][ni], 0, 0, 0);
  }
#pragma unroll
  for (int mi = 0; mi < 2; mi++)
#pragma unroll
    for (int ni = 0; ni < 2; ni++) {
      int m = wm * 32 + mi * 16 + (lane >> 4) * 4;
      int n = g0 + wn * 32 + ni * 16 + (lane & 15);
#pragma unroll
      for (int r = 0; r < 4; r++)
        P.xww[(size_t)(tb0 + m + r) * G4 + n] = cacc[mi][ni][r];
    }
}

__global__ __launch_bounds__(512)
__attribute__((amdgpu_waves_per_eu(2, 2)))
void fused_kernel(Params P) {
  __shared__ Smem S;
  int bid = blockIdx.x;
  if (bid < 64)        role_rec<0>(S.r, P.L, P, bid);
  else if (bid < 128)  role_rec<1>(S.r, P.L - 2, P, bid - 64);
  else                 role_gemm(S.g, P.L - 1, P);
}

// ---------------------------------------------------------------------------
__global__ void prep_kernel(const float* Wih0, const float* Whh0,
                            const float* bih0, const float* bhh0,
                            const float* Wih1, const float* Whh1,
                            const float* bih1, const float* bhh1,
                            const float* Whead, const float* bhead,
                            __half* wh0, __half* wh1, __half* wi1, __half* wi0,
                            __half* whd, float* bs0, float* bs1, float* bhd) {
  int i = blockIdx.x * blockDim.x + threadIdx.x;
  if (i < G4 * HID) {
    wh0[i] = __float2half(Whh0[i]);
    wh1[i] = __float2half(Whh1[i]);
    wi1[i] = __float2half(Wih1[i]);
  }
  if (i < G4 * INCH) wi0[i] = __float2half(Wih0[i]);
  if (i < OC * HID)  whd[i] = __float2half(Whead[i]);
  if (i < G4) { bs0[i] = bih0[i] + bhh0[i]; bs1[i] = bih1[i] + bhh1[i]; }
  if (i < OC) bhd[i] = bhead[i];
}

// ---------------------------------------------------------------------------
extern "C" void kernel_launch(void* const* d_in, const int* in_sizes, int n_in,
                              void* d_out, int out_size, void* d_ws, size_t ws_size,
                              hipStream_t stream) {
  const float* x     = (const float*)d_in[0];
  const float* Wih0  = (const float*)d_in[1];
  const float* Whh0  = (const float*)d_in[2];
  const float* bih0  = (const float*)d_in[3];
  const float* bhh0  = (const float*)d_in[4];
  const float* Wih1  = (const float*)d_in[5];
  const float* Whh1  = (const float*)d_in[6];
  const float* bih1  = (const float*)d_in[7];
  const float* bhh1  = (const float*)d_in[8];
  const float* Whead = (const float*)d_in[9];
  const float* bhead = (const float*)d_in[10];
  float* y = (float*)d_out;

  char* ws = (char*)d_ws;
  size_t cur = 0;
  auto alloc = [&](size_t sz) -> char* {
    char* p = ws + cur;
    cur = (cur + sz + 255) & ~(size_t)255;
    return p;
  };
  __half* wh0 = (__half*)alloc(G4 * HID * 2);
  __half* wh1 = (__half*)alloc(G4 * HID * 2);
  __half* wi1 = (__half*)alloc(G4 * HID * 2);
  __half* wi0 = (__half*)alloc(G4 * INCH * 2);
  __half* whd = (__half*)alloc(OC * HID * 2);
  float* bs0 = (float*)alloc(G4 * 4);
  float* bs1 = (float*)alloc(G4 * 4);
  float* bhd = (float*)alloc(OC * 4);
  float* h0s = (float*)alloc(NB * HID * 4);
  float* c0s = (float*)alloc(NB * HID * 4);
  float* h1s = (float*)alloc(NB * HID * 4);
  float* c1s = (float*)alloc(NB * HID * 4);
  size_t fixed = cur;

  // Tc=128: minimizes total steps (T + 2*Tc) while keeping per-dispatch
  // prologue amortization acceptable; xw working set becomes L3-resident.
  int Tc = 128;
  while (Tc > 64) {
    size_t need = fixed + 2 * ((size_t)Tc * NB * HID * 2 + 512) +
                  2 * ((size_t)Tc * NB * G4 * 4 + 512);
    if (need <= ws_size) break;
    Tc >>= 1;
  }
  __half* h1buf[2];
  float* xwbuf[2];
  h1buf[0] = (__half*)alloc((size_t)Tc * NB * HID * 2);
  h1buf[1] = (__half*)alloc((size_t)Tc * NB * HID * 2);
  xwbuf[0] = (float*)alloc((size_t)Tc * NB * G4 * 4);
  xwbuf[1] = (float*)alloc((size_t)Tc * NB * G4 * 4);

  const int nch = T_SEQ / Tc;

  prep_kernel<<<(G4 * HID + 255) / 256, 256, 0, stream>>>(
      Wih0, Whh0, bih0, bhh0, Wih1, Whh1, bih1, bhh1, Whead, bhead,
      wh0, wh1, wi1, wi0, whd, bs0, bs1, bhd);

  const int ngemm = Tc * 8;
  for (int L = 0; L < nch + 2; ++L) {
    Params P;
    P.x = x;
    P.wh0 = wh0; P.wh1 = wh1; P.wi0 = wi0; P.wi1 = wi1; P.whd = whd;
    P.bs0 = bs0; P.bs1 = bs1; P.bhd = bhd;
    P.h0s = h0s; P.c0s = c0s; P.h1s = h1s; P.c1s = c1s;
    P.h1w = h1buf[L & 1];
    P.h1r = h1buf[(L + 1) & 1];
    P.xww = xwbuf[(L + 1) & 1];
    P.xwr = xwbuf[L & 1];
    P.y = y;
    P.L = L; P.Tc = Tc; P.nch = nch;
    fused_kernel<<<128 + ngemm, 512, 0, stream>>>(P);
  }
}